// Round 9
// baseline (362.486 us; speedup 1.0000x reference)
//
#include <hip/hip_runtime.h>

// GCN fused pipeline. Round 9: T3/T4-style counted-vmcnt pipeline in mfma_tn.
// 2-deep register prefetch + double LDS buffer + RAW s_barrier (lgkmcnt(0)
// only) so global loads stay in flight across barriers — __syncthreads's
// forced vmcnt(0) drain was the R5-R8 bottleneck (all pipes idle, HBM 42%).
// Steady state: 24 VMEM in flight, vmcnt(12) waits only for the older set.
//
//   K1 gemm_w1t   : [pre|cur]@W1 with fused transpose-bf16 epilogue -> pwT/cwT
//   K2 mfma_tn<3> : z<4: pre1 partials (adj@cwT, fp32 row staging);
//                   z>=4: cur1 partials (adjT@pwT, in-stage transpose)
//   K3 rln        : stacked reduce+leaky+invnorm -> c1,p1, inc1,inp1
//   K4 gemm32     : stacked [c1;p1]@W2 -> [cw2;pw2]
//   K5 gemm32     : stacked brackets   K6 reduce_mcmp   K7 gemm32 EPI3 tails
//   K8 mfma_tn<0> : adj2 = p2n @ c2n^T -> d_out (NT stores)
//
// adj1 (8192x8192 cosine-sim intermediate) is NEVER materialized:
//   adj1 @ cur_w2   = Dp^-1 * pre1 * [ (Dc^-1 cur1)^T @ cur_w2 ]  (128x128)
//   adj1^T @ pre_w2 = Dc^-1 * cur1 * [ (Dp^-1 pre1)^T @ pre_w2 ]  (128x128)

#define NN 8192
#define DD 128

typedef __bf16 bf16x8 __attribute__((ext_vector_type(8)));
typedef float f32x4 __attribute__((ext_vector_type(4)));

static __device__ __forceinline__ float4 ldg4(const float* p) {
    return *reinterpret_cast<const float4*>(p);
}

// Pack 2 floats -> 2 bf16 in a u32 (compiler emits v_cvt_pk_bf16_f32).
static __device__ __forceinline__ unsigned f2bf2(float lo, float hi) {
    __bf16 a = (__bf16)lo, b = (__bf16)hi;
    unsigned short ua = __builtin_bit_cast(unsigned short, a);
    unsigned short ub = __builtin_bit_cast(unsigned short, b);
    return (unsigned)ua | ((unsigned)ub << 16);
}

// compile-time component select of a float4 (j folds in unrolled loops)
#define FC(v, j) ((j) == 0 ? (v).x : (j) == 1 ? (v).y : (j) == 2 ? (v).z : (v).w)

// LDS 16B-slot swizzle: byte_off ^= swz16(row); keeps every staging write and
// fragment read <= 2-way (free) for all access modes here.
static __device__ __forceinline__ int swz16(int row) {
    return (((row & 7) ^ ((row >> 3) & 7)) << 4);
}

#define PRAGU _Pragma("unroll")

// ---------------------------------------------------------------------------
// MFMA GEMM:  C[i,j] (+)= sum_k opA[i,k] * B[k,j],  B given as BT[n][k] bf16.
//   AMODE 0: A bf16 row-major [M][K]       (final GEMM; NT stores). NV=8.
//   AMODE 3: combined adj pass. z<4: opA = adj (fp32 row-major, bf16-convert
//            in staging), BT=BTa, k-slice z. z>=4: opA = adj^T (fp32, in-stage
//            register transpose), BT=BTb, k-slice z-4. NV=12 VMEM/set.
// Block tile 128x128, BK=64, 4 waves, mfma_f32_16x16x32_bf16.
// Pipeline: 2 reg sets (A/B) + 2 LDS buffers; counted s_waitcnt vmcnt(NV);
// raw s_barrier preceded by lgkmcnt(0) only (global loads NOT drained);
// sched_barrier(0) after each barrier pins ds_read ordering (rule #18).
// Tile t lives in buf[t&1]; nt is even for all users (32 and 2).
// ---------------------------------------------------------------------------
template<int AMODE>
__global__ __launch_bounds__(256, 2)
void mfma_tn(const void* __restrict__ Aptr, int lda,
             const unsigned short* __restrict__ BTa,
             const unsigned short* __restrict__ BTb, int ldbt,
             float* __restrict__ C, int ldc,
             int ksplit, int zstride)
{
    __shared__ alignas(16) char smem[65536];   // 2 x (16K sA | 16K sB)

    const int t    = threadIdx.x;
    const int l    = t & 63;
    const int w    = t >> 6;
    const int wr   = (w >> 1) * 64;
    const int wc   = (w & 1) * 64;
    const int lrow = l & 15;
    const int lhi  = l >> 4;
    const int i0   = blockIdx.x * 128;
    const int j0   = blockIdx.y * 128;
    const int z    = blockIdx.z;
    const bool second = (AMODE == 3) && (z >= 4);
    const unsigned short* BT = second ? BTb : BTa;
    const int kbase = (AMODE == 3) ? (z & 3) * ksplit : 0;
    C += (size_t)z * (size_t)zstride;

    const int srow = t >> 3;   // 0..31 (row-major staging)
    const int skg  = t & 7;    // 16B slot along k
    const int u    = t & 31;   // AMODE3-second: col group
    const int r8   = t >> 5;   // AMODE3-second: k-octet

    f32x4 acc[4][4];
    PRAGU
    for (int r = 0; r < 4; ++r)
        PRAGU
        for (int q = 0; q < 4; ++q)
            PRAGU
            for (int e = 0; e < 4; ++e) acc[r][q][e] = 0.0f;

    // two statically-named register sets (rule #20: no runtime set index)
    float4 faA[8], faB[8];
    uint4  uaA[4], uaB[4];
    uint4  ubA[4], ubB[4];

#define LOADM(kk_, fa_, ua_, ub_)                                              \
    do {                                                                       \
        const int kk__ = (kk_);                                                \
        if constexpr (AMODE == 3) {                                            \
            if (second) {                                                      \
                const float* gA_ = (const float*)Aptr;                         \
                PRAGU for (int e = 0; e < 8; ++e)                              \
                    fa_[e] = ldg4(&gA_[(size_t)(kk__ + r8 * 8 + e) * lda + i0 + u * 4]); \
            } else {                                                           \
                PRAGU for (int it = 0; it < 4; ++it) {                         \
                    const float* g_ = (const float*)Aptr +                     \
                        (size_t)(i0 + it * 32 + srow) * lda + kk__ + skg * 8;  \
                    fa_[2 * it] = ldg4(g_); fa_[2 * it + 1] = ldg4(g_ + 4);    \
                }                                                              \
            }                                                                  \
        } else {                                                               \
            PRAGU for (int it = 0; it < 4; ++it)                               \
                ua_[it] = *reinterpret_cast<const uint4*>(                     \
                    (const unsigned short*)Aptr +                              \
                    (size_t)(i0 + it * 32 + srow) * lda + kk__ + skg * 8);     \
        }                                                                      \
        PRAGU for (int it = 0; it < 4; ++it)                                   \
            ub_[it] = *reinterpret_cast<const uint4*>(                         \
                BT + (size_t)(j0 + it * 32 + srow) * ldbt + kk__ + skg * 8);   \
    } while (0)

#define WRITEM(buf_, fa_, ua_, ub_)                                            \
    do {                                                                       \
        char* smA_ = smem + (buf_) * 32768;                                    \
        char* smB_ = smA_ + 16384;                                             \
        if constexpr (AMODE == 3) {                                            \
            if (second) {                                                      \
                PRAGU for (int j = 0; j < 4; ++j) {                            \
                    const int c_ = u * 4 + j;                                  \
                    uint4 wv_;                                                 \
                    wv_.x = f2bf2(FC(fa_[0], j), FC(fa_[1], j));               \
                    wv_.y = f2bf2(FC(fa_[2], j), FC(fa_[3], j));               \
                    wv_.z = f2bf2(FC(fa_[4], j), FC(fa_[5], j));               \
                    wv_.w = f2bf2(FC(fa_[6], j), FC(fa_[7], j));               \
                    *reinterpret_cast<uint4*>(smA_ + c_ * 128 + ((r8 << 4) ^ swz16(c_))) = wv_; \
                }                                                              \
            } else {                                                           \
                PRAGU for (int it = 0; it < 4; ++it) {                         \
                    const int row_ = it * 32 + srow;                           \
                    uint4 wv_;                                                 \
                    wv_.x = f2bf2(fa_[2 * it].x, fa_[2 * it].y);               \
                    wv_.y = f2bf2(fa_[2 * it].z, fa_[2 * it].w);               \
                    wv_.z = f2bf2(fa_[2 * it + 1].x, fa_[2 * it + 1].y);       \
                    wv_.w = f2bf2(fa_[2 * it + 1].z, fa_[2 * it + 1].w);       \
                    *reinterpret_cast<uint4*>(smA_ + row_ * 128 + ((skg << 4) ^ swz16(row_))) = wv_; \
                }                                                              \
            }                                                                  \
        } else {                                                               \
            PRAGU for (int it = 0; it < 4; ++it) {                             \
                const int row_ = it * 32 + srow;                               \
                *reinterpret_cast<uint4*>(smA_ + row_ * 128 + ((skg << 4) ^ swz16(row_))) = ua_[it]; \
            }                                                                  \
        }                                                                      \
        PRAGU for (int it = 0; it < 4; ++it) {                                 \
            const int row_ = it * 32 + srow;                                   \
            *reinterpret_cast<uint4*>(smB_ + row_ * 128 + ((skg << 4) ^ swz16(row_))) = ub_[it]; \
        }                                                                      \
    } while (0)

// counted waits: NV = VMEM instrs per LOADM set (12 for AMODE3, 8 for AMODE0)
#define WAITNV()                                                               \
    do { if constexpr (AMODE == 3)                                             \
             asm volatile("s_waitcnt vmcnt(12)" ::: "memory");                 \
         else                                                                  \
             asm volatile("s_waitcnt vmcnt(8)" ::: "memory"); } while (0)
#define WAIT0() asm volatile("s_waitcnt vmcnt(0)" ::: "memory")

// producer barrier: ds_writes visible, global loads stay in flight
#define BARRIER()                                                              \
    do { asm volatile("s_waitcnt lgkmcnt(0)" ::: "memory");                    \
         __builtin_amdgcn_s_barrier();                                         \
         __builtin_amdgcn_sched_barrier(0); } while (0)

    auto MFMA_STEP = [&](const int buf) {
        char* smA = smem + buf * 32768;
        char* smB = smA + 16384;
        PRAGU
        for (int s = 0; s < 2; ++s) {
            bf16x8 af[4], bq[4];
            PRAGU
            for (int r = 0; r < 4; ++r) {
                const int row = wr + r * 16 + lrow;
                af[r] = *reinterpret_cast<const bf16x8*>(
                    smA + row * 128 + ((s * 64 + lhi * 16) ^ swz16(row)));
            }
            PRAGU
            for (int q = 0; q < 4; ++q) {
                const int col = wc + q * 16 + lrow;
                bq[q] = *reinterpret_cast<const bf16x8*>(
                    smB + col * 128 + ((s * 64 + lhi * 16) ^ swz16(col)));
            }
            PRAGU
            for (int r = 0; r < 4; ++r)
                PRAGU
                for (int q = 0; q < 4; ++q)
                    acc[r][q] = __builtin_amdgcn_mfma_f32_16x16x32_bf16(af[r], bq[q], acc[r][q], 0, 0, 0);
        }
    };

    // ---- prologue: tiles 0,1 issued; write tile 0 ----
    const int nt = ksplit >> 6;              // 32 (K2) or 2 (K8) — even
    LOADM(kbase, faA, uaA, ubA);
    LOADM(kbase + 64, faB, uaB, ubB);
    WAITNV();                                // tile 0's loads done
    WRITEM(0, faA, uaA, ubA);
    BARRIER();

    // ---- main loop, 2 tiles per iteration; tile t in buf[t&1] ----
    for (int tt = 0; tt < nt; tt += 2) {
        MFMA_STEP(0);                        // tile tt
        if (tt + 2 < nt) { LOADM(kbase + (tt + 2) * 64, faA, uaA, ubA); WAITNV(); }
        else             { WAIT0(); }
        WRITEM(1, faB, uaB, ubB);            // tile tt+1 -> buf1
        BARRIER();
        MFMA_STEP(1);                        // tile tt+1
        if (tt + 2 < nt) {
            LOADM(kbase + (tt + 3) * 64, faB, uaB, ubB);
            WAITNV();                        // tile tt+2's loads done
            WRITEM(0, faA, uaA, ubA);        // tile tt+2 -> buf0
            BARRIER();
        }
    }
    __syncthreads();                         // full drain before smem reuse

    // ---- epilogue: sC[128][68] roundtrip -> coalesced float4 stores ----
    float* sC = (float*)smem;
    PRAGU
    for (int h = 0; h < 2; ++h) {
        if ((w & 1) == h) {
            PRAGU
            for (int r = 0; r < 4; ++r)
                PRAGU
                for (int q = 0; q < 4; ++q)
                    PRAGU
                    for (int i = 0; i < 4; ++i)
                        sC[(wr + r * 16 + lhi * 4 + i) * 68 + q * 16 + lrow] = acc[r][q][i];
        }
        __syncthreads();
        PRAGU
        for (int it = 0; it < 8; ++it) {
            const int idx = it * 256 + t;
            const int row = idx >> 4;
            const int c4  = (idx & 15) << 2;
            f32x4 v = *reinterpret_cast<const f32x4*>(&sC[row * 68 + c4]);
            float* dst = &C[(size_t)(i0 + row) * ldc + j0 + h * 64 + c4];
            if constexpr (AMODE == 0)
                __builtin_nontemporal_store(v, reinterpret_cast<f32x4*>(dst));
            else
                *reinterpret_cast<f32x4*>(dst) = v;
        }
        __syncthreads();
    }
#undef LOADM
#undef WRITEM
#undef WAITNV
#undef WAIT0
#undef BARRIER
}

// ---------------------------------------------------------------------------
// K1: [pre|cur] @ W1 with fused transpose-bf16 epilogue.
// blockIdx.x < 256 -> pre rows -> pwT ; >= 256 -> cur rows -> cwT.
// ---------------------------------------------------------------------------
__global__ __launch_bounds__(256, 2)
void gemm_w1t(const float* __restrict__ pre, const float* __restrict__ cur,
              const float* __restrict__ W1,
              unsigned short* __restrict__ pwT, unsigned short* __restrict__ cwT)
{
    __shared__ float sA[32][68];
    __shared__ float sB[64][128];            // reused as sC[32][128]

    const int t  = threadIdx.x;
    const int ct = t & 31;
    const int rt = t >> 5;
    const int bx = blockIdx.x;
    const bool isCur = bx >= 256;
    const float* A = isCur ? cur : pre;
    unsigned short* XT = isCur ? cwT : pwT;
    const int i0 = (bx & 255) * 32;

    float4 acc[4];
    #pragma unroll
    for (int r = 0; r < 4; ++r) { acc[r].x = 0.f; acc[r].y = 0.f; acc[r].z = 0.f; acc[r].w = 0.f; }

    for (int k0 = 0; k0 < DD; k0 += 64) {
        #pragma unroll
        for (int f = 0; f < 2; ++f) {
            const int row = (t >> 4) + 16 * f;
            const int kk4 = (t & 15) << 2;
            *reinterpret_cast<float4*>(&sA[row][kk4]) =
                ldg4(&A[(size_t)(i0 + row) * DD + k0 + kk4]);
        }
        #pragma unroll
        for (int f = 0; f < 8; ++f) {
            const int idx = f * 256 + t;
            const int kk  = idx >> 5;
            const int c4  = (idx & 31) << 2;
            *reinterpret_cast<float4*>(&sB[kk][c4]) =
                ldg4(&W1[(size_t)(k0 + kk) * DD + c4]);
        }
        __syncthreads();
        #pragma unroll 4
        for (int kk = 0; kk < 64; kk += 4) {
            float4 a[4], b[4];
            #pragma unroll
            for (int r = 0; r < 4; ++r)
                a[r] = *reinterpret_cast<const float4*>(&sA[rt * 4 + r][kk]);
            #pragma unroll
            for (int q = 0; q < 4; ++q)
                b[q] = *reinterpret_cast<const float4*>(&sB[kk + q][ct * 4]);
            #pragma unroll
            for (int r = 0; r < 4; ++r) {
                acc[r].x += a[r].x * b[0].x; acc[r].y += a[r].x * b[0].y;
                acc[r].z += a[r].x * b[0].z; acc[r].w += a[r].x * b[0].w;
                acc[r].x += a[r].y * b[1].x; acc[r].y += a[r].y * b[1].y;
                acc[r].z += a[r].y * b[1].z; acc[r].w += a[r].y * b[1].w;
                acc[r].x += a[r].z * b[2].x; acc[r].y += a[r].z * b[2].y;
                acc[r].z += a[r].z * b[2].z; acc[r].w += a[r].z * b[2].w;
                acc[r].x += a[r].w * b[3].x; acc[r].y += a[r].w * b[3].y;
                acc[r].z += a[r].w * b[3].z; acc[r].w += a[r].w * b[3].w;
            }
        }
        __syncthreads();
    }

    // Transpose epilogue: acc -> sC[32][128] f32 -> bf16 XT[n][i0..i0+31]
    float* sC = &sB[0][0];
    #pragma unroll
    for (int r = 0; r < 4; ++r)
        *reinterpret_cast<float4*>(&sC[(rt * 4 + r) * 128 + ct * 4]) = acc[r];
    __syncthreads();

    const int n = t & 127;
    const int g = t >> 7;
    #pragma unroll
    for (int c = 0; c < 2; ++c) {
        const int ii = (2 * g + c) * 8;
        uint4 wv;
        wv.x = f2bf2(sC[(ii + 0) * 128 + n], sC[(ii + 1) * 128 + n]);
        wv.y = f2bf2(sC[(ii + 2) * 128 + n], sC[(ii + 3) * 128 + n]);
        wv.z = f2bf2(sC[(ii + 4) * 128 + n], sC[(ii + 5) * 128 + n]);
        wv.w = f2bf2(sC[(ii + 6) * 128 + n], sC[(ii + 7) * 128 + n]);
        *reinterpret_cast<uint4*>(&XT[(size_t)n * NN + i0 + ii]) = wv;
    }
}

// ---------------------------------------------------------------------------
// K3: stacked split-K reduce + leaky ReLU + inverse row norm.
// blockIdx.y = 0 -> c1 (kparts slots 4..7), 1 -> p1 (slots 0..3).
// ---------------------------------------------------------------------------
__global__ __launch_bounds__(128)
void rln(const float* __restrict__ kparts, float* __restrict__ Xbase,
         float* __restrict__ invbase)
{
    const int i = blockIdx.x;
    const int y = blockIdx.y;
    const int t = threadIdx.x;
    const float* part = kparts + (size_t)(1 - y) * 4 * (NN * DD);
    float* X = Xbase + (size_t)y * (NN * DD);
    float* inv_n = invbase + y * NN;

    float s = 0.f;
    #pragma unroll
    for (int z = 0; z < 4; ++z)
        s += part[(size_t)z * (NN * DD) + (size_t)i * DD + t];
    float y_ = (s >= 0.f) ? s : 0.01f * s;
    X[(size_t)i * DD + t] = y_;
    float n = y_ * y_;
    #pragma unroll
    for (int o = 32; o > 0; o >>= 1) n += __shfl_down(n, o);
    __shared__ float p[2];
    if ((t & 63) == 0) p[t >> 6] = n;
    __syncthreads();
    if (t == 0) inv_n[i] = 1.0f / sqrtf(p[0] + p[1]);
}

// ---------------------------------------------------------------------------
// fp32 tiled GEMM, N=128 fixed (j0=0); blockIdx.y = side with element strides
// ystA/ystB/ystC/ystS; blockIdx.z = split-K slice (C += z*zstride, EPI0).
//   EPI 0: raw fp32 store to C
//   EPI 3: y=leaky(acc*rscale[row]); row-norm via 32-lane shfl; bf16 to Cb.
//   SCALEK (with TRANSA): A *= kscale[k] during staging.
// ---------------------------------------------------------------------------
template<bool TRANSA, bool SCALEK, int EPI>
__global__ __launch_bounds__(256, 2)
void gemm32(const float* __restrict__ A, int lda,
            const float* __restrict__ B, int ldb,
            float* __restrict__ C, unsigned short* __restrict__ Cb,
            int ksplit_len, int zstride,
            const float* __restrict__ kscale,
            const float* __restrict__ rscale,
            int ystA, int ystB, int ystC, int ystS)
{
    __shared__ float sA[32][68];
    __shared__ float sB[64][128];

    const int t  = threadIdx.x;
    const int ct = t & 31;
    const int rt = t >> 5;
    const int i0 = blockIdx.x * 32;
    const int side = blockIdx.y;
    const int kgbase = blockIdx.z * ksplit_len;

    A += (ptrdiff_t)side * ystA;
    B += (ptrdiff_t)side * ystB;
    if constexpr (EPI == 0)
        C += (ptrdiff_t)side * ystC + (size_t)blockIdx.z * (size_t)zstride;
    if constexpr (EPI == 3)
        Cb += (ptrdiff_t)side * ystC;
    if constexpr (SCALEK) kscale += (ptrdiff_t)side * ystS;
    if constexpr (EPI == 3) rscale += (ptrdiff_t)side * ystS;

    float4 acc[4];
    #pragma unroll
    for (int r = 0; r < 4; ++r) { acc[r].x = 0.f; acc[r].y = 0.f; acc[r].z = 0.f; acc[r].w = 0.f; }

    for (int k0 = 0; k0 < ksplit_len; k0 += 64) {
        const int kg = kgbase + k0;
        if (!TRANSA) {
            #pragma unroll
            for (int f = 0; f < 2; ++f) {
                const int row = (t >> 4) + 16 * f;
                const int kk4 = (t & 15) << 2;
                *reinterpret_cast<float4*>(&sA[row][kk4]) =
                    ldg4(&A[(size_t)(i0 + row) * lda + kg + kk4]);
            }
        } else {
            #pragma unroll
            for (int f = 0; f < 2; ++f) {
                const int kk = (t >> 3) + 32 * f;
                const int r4 = (t & 7) << 2;
                float4 v = ldg4(&A[(size_t)(kg + kk) * lda + i0 + r4]);
                if (SCALEK) {
                    const float s = kscale[kg + kk];
                    v.x *= s; v.y *= s; v.z *= s; v.w *= s;
                }
                sA[r4 + 0][kk] = v.x; sA[r4 + 1][kk] = v.y;
                sA[r4 + 2][kk] = v.z; sA[r4 + 3][kk] = v.w;
            }
        }
        #pragma unroll
        for (int f = 0; f < 8; ++f) {
            const int idx = f * 256 + t;
            const int kk  = idx >> 5;
            const int c4  = (idx & 31) << 2;
            *reinterpret_cast<float4*>(&sB[kk][c4]) =
                ldg4(&B[(size_t)(kg + kk) * ldb + c4]);
        }
        __syncthreads();
        #pragma unroll 4
        for (int kk = 0; kk < 64; kk += 4) {
            float4 a[4], b[4];
            #pragma unroll
            for (int r = 0; r < 4; ++r)
                a[r] = *reinterpret_cast<const float4*>(&sA[rt * 4 + r][kk]);
            #pragma unroll
            for (int q = 0; q < 4; ++q)
                b[q] = *reinterpret_cast<const float4*>(&sB[kk + q][ct * 4]);
            #pragma unroll
            for (int r = 0; r < 4; ++r) {
                acc[r].x += a[r].x * b[0].x; acc[r].y += a[r].x * b[0].y;
                acc[r].z += a[r].x * b[0].z; acc[r].w += a[r].x * b[0].w;
                acc[r].x += a[r].y * b[1].x; acc[r].y += a[r].y * b[1].y;
                acc[r].z += a[r].y * b[1].z; acc[r].w += a[r].y * b[1].w;
                acc[r].x += a[r].z * b[2].x; acc[r].y += a[r].z * b[2].y;
                acc[r].z += a[r].z * b[2].z; acc[r].w += a[r].z * b[2].w;
                acc[r].x += a[r].w * b[3].x; acc[r].y += a[r].w * b[3].y;
                acc[r].z += a[r].w * b[3].z; acc[r].w += a[r].w * b[3].w;
            }
        }
        __syncthreads();
    }

    #pragma unroll
    for (int r = 0; r < 4; ++r) {
        const int rg = i0 + rt * 4 + r;
        if constexpr (EPI == 3) {
            const float s = rscale[rg];
            float y0 = acc[r].x * s, y1 = acc[r].y * s,
                  y2 = acc[r].z * s, y3 = acc[r].w * s;
            y0 = (y0 >= 0.f) ? y0 : 0.01f * y0;
            y1 = (y1 >= 0.f) ? y1 : 0.01f * y1;
            y2 = (y2 >= 0.f) ? y2 : 0.01f * y2;
            y3 = (y3 >= 0.f) ? y3 : 0.01f * y3;
            float ss = y0 * y0 + y1 * y1 + y2 * y2 + y3 * y3;
            #pragma unroll
            for (int m = 16; m > 0; m >>= 1) ss += __shfl_xor(ss, m);
            const float invn = rsqrtf(ss);
            uint2 wv;
            wv.x = f2bf2(y0 * invn, y1 * invn);
            wv.y = f2bf2(y2 * invn, y3 * invn);
            *reinterpret_cast<uint2*>(&Cb[(size_t)rg * DD + ct * 4]) = wv;
        } else {
            *reinterpret_cast<float4*>(&C[(size_t)rg * DD + ct * 4]) = acc[r];
        }
    }
}

// ---------------------------------------------------------------------------
// K6: stacked reduce for the brackets: out[y][i] = sum_z part[y][z][i].
// ---------------------------------------------------------------------------
__global__ __launch_bounds__(256)
void reduce_mcmp(const float* __restrict__ part, float* __restrict__ out)
{
    const int y = blockIdx.y;
    const int i = blockIdx.x * 256 + threadIdx.x;   // 0..16383
    part += (size_t)y * 32 * 16384;
    out  += (size_t)y * 16384;
    float a = 0.f;
    #pragma unroll
    for (int z = 0; z < 32; ++z) a += part[(size_t)z * 16384 + i];
    out[i] = a;
}

// ---------------------------------------------------------------------------
extern "C" void kernel_launch(void* const* d_in, const int* in_sizes, int n_in,
                              void* d_out, int out_size, void* d_ws, size_t ws_size,
                              hipStream_t stream)
{
    const float* pre = (const float*)d_in[0];
    const float* cur = (const float*)d_in[1];
    const float* adj = (const float*)d_in[2];
    const float* W1  = (const float*)d_in[3];
    const float* W2  = (const float*)d_in[4];
    float* out = (float*)d_out;
    float* ws  = (float*)d_ws;

    const size_t M1 = (size_t)NN * DD;   // 1,048,576

    // ws layout (~64 MB of 1 GiB); d_out untouched until K8.
    float* cwpw2 = ws + 0 * M1;                               // [cw2; pw2] 2*M1
    float* c1    = ws + 2 * M1;                               // c1 then p1 (contig)
    unsigned short* c2n_b = (unsigned short*)(ws + 4 * M1);   // c2n then p2n (bf16)
    unsigned short* p2n_b = c2n_b + M1;
    unsigned short* cwT_b = (unsigned short*)(ws + 5 * M1);   // [128][8192] bf16
    unsigned short* pwT_b = cwT_b + M1;
    float* bparts = ws + 6 * M1;                              // [2][32][16384]
    float* mcmp   = ws + 7 * M1;                              // [mc; mp] 32768
    float* inc1   = mcmp + 32768;                             // inc1 then inp1
    float* kparts = ws + 8 * M1;                              // [8][M1]

    // K1: [pre|cur]@W1 -> pwT_b / cwT_b (transposed bf16, no fp32 store)
    gemm_w1t<<<dim3(512,1,1),256,0,stream>>>(pre, cur, W1, pwT_b, cwT_b);

    // K2: combined adj pass, split-K 4 per side (512 blocks = 2/CU resident,
    //     one full round). z<4: pre1 partials (adj@cwT) -> kparts[0..3];
    //     z>=4: cur1 partials (adjT@pwT) -> kparts[4..7].
    mfma_tn<3><<<dim3(64,1,8),256,0,stream>>>(adj, NN, cwT_b, pwT_b, NN,
                                              kparts, DD, NN/4, (int)M1);

    // K3: stacked reduce+leaky+invnorm: y=0 -> c1/inc1, y=1 -> p1/inp1
    rln<<<dim3(NN,2,1),128,0,stream>>>(kparts, c1, inc1);

    // K4: [c1;p1]@W2 -> [cw2;pw2] (single M=16384 GEMM)
    gemm32<false,false,0><<<dim3(512,1,1),256,0,stream>>>(
        c1, DD, W2, DD, cwpw2, (unsigned short*)nullptr,
        DD, 0, nullptr, nullptr, 0,0,0,0);

    // K5: stacked brackets: side0 mc = (Dc^-1 c1)^T@cw2, side1 mp = (Dp^-1 p1)^T@pw2
    gemm32<true,true,0><<<dim3(4,2,32),256,0,stream>>>(
        c1, DD, cwpw2, DD, bparts, (unsigned short*)nullptr,
        256, 16384, inc1, nullptr,
        (int)M1, (int)M1, 32*16384, NN);

    // K6: stacked split-K reduce -> mcmp = [mc; mp]
    reduce_mcmp<<<dim3(64,2,1),256,0,stream>>>(bparts, mcmp);

    // K7: stacked fused tails (EPI3):
    //   side0: c2n = normrows(leaky(Dc^-1 c1 @ mp)) ; side1: p2n = ... (mc)
    gemm32<false,false,3><<<dim3(256,2,1),256,0,stream>>>(
        c1, DD, mcmp + 16384, DD, (float*)nullptr, c2n_b,
        DD, 0, nullptr, inc1,
        (int)M1, -16384, (int)M1, NN);

    // K8: adj2 = p2n @ c2n^T -> d_out (NT stores)
    mfma_tn<0><<<dim3(64,64,1),256,0,stream>>>(p2n_b, DD, c2n_b, c2n_b, DD,
                                               out, NN, DD, 0);
}

// Round 10
// 300.321 us; speedup vs baseline: 1.2070x; 1.2070x over previous
//
#include <hip/hip_runtime.h>

// GCN fused pipeline. Round 10: revert to R8 base (best wall, 284.6); two
// surgical kernel right-sizings:
//   K8 -> mfma_out: K=128 single-stage, ONE barrier, direct stores (the old
//         path spent ~6 barrier drains + an LDS-roundtrip on 2 K-steps).
//   K2 -> mfma_adj: BK=128 chunks (half the vmcnt(0) drains/block), 64KB LDS.
//
//   K1 gemm_w1t   : [pre|cur]@W1 with fused transpose-bf16 epilogue -> pwT/cwT
//   K2 mfma_adj   : z<8: pre1 partials (adj@cwT, fp32 row staging);
//                   z>=8: cur1 partials (adjT@pwT, in-stage transpose)
//   K3 rln        : stacked reduce+leaky+invnorm -> c1,p1, inc1,inp1
//   K4 gemm32     : stacked [c1;p1]@W2 -> [cw2;pw2]
//   K5 gemm32     : stacked brackets   K6 reduce_mcmp   K7 gemm32 EPI3 tails
//   K8 mfma_out   : adj2 = p2n @ c2n^T -> d_out
//
// adj1 (8192x8192 cosine-sim intermediate) is NEVER materialized:
//   adj1 @ cur_w2   = Dp^-1 * pre1 * [ (Dc^-1 cur1)^T @ cur_w2 ]  (128x128)
//   adj1^T @ pre_w2 = Dc^-1 * cur1 * [ (Dp^-1 pre1)^T @ pre_w2 ]  (128x128)

#define NN 8192
#define DD 128

typedef __bf16 bf16x8 __attribute__((ext_vector_type(8)));
typedef float f32x4 __attribute__((ext_vector_type(4)));

static __device__ __forceinline__ float4 ldg4(const float* p) {
    return *reinterpret_cast<const float4*>(p);
}

// Pack 2 floats -> 2 bf16 in a u32 (compiler emits v_cvt_pk_bf16_f32).
static __device__ __forceinline__ unsigned f2bf2(float lo, float hi) {
    __bf16 a = (__bf16)lo, b = (__bf16)hi;
    unsigned short ua = __builtin_bit_cast(unsigned short, a);
    unsigned short ub = __builtin_bit_cast(unsigned short, b);
    return (unsigned)ua | ((unsigned)ub << 16);
}

// compile-time component select of a float4 (j folds in unrolled loops)
#define FC(v, j) ((j) == 0 ? (v).x : (j) == 1 ? (v).y : (j) == 2 ? (v).z : (v).w)

#define PRAGU _Pragma("unroll")

// LDS swizzle for [row][128k] bf16 tiles (256B rows, 16 x 16B slots/row):
// bit3 of slot (k-half) preserved, low 3 slot bits XOR'd with row hash ->
// every staging write and fragment read <= 2-way (free).
static __device__ __forceinline__ int swz16(int row) {
    return (((row & 7) ^ ((row >> 3) & 7)) << 4);
}
static __device__ __forceinline__ int lslot(int row, int slot) {
    return ((slot & 8) << 4) | (((slot & 7) << 4) ^ swz16(row));
}

// ---------------------------------------------------------------------------
// K2: combined adj pass.  C[i,j](z) = sum_{k in slice z} opA[i,k] * B[k,j]
//   z < 8 : opA = adj (fp32 row-major, bf16-convert in staging), BT = BTa
//   z >= 8: opA = adj^T (fp32, in-stage register transpose),     BT = BTb
// Block tile 128x128(N=128 total), BK=128, 4 waves, mfma 16x16x32 bf16.
// Single 64KB stage (A 32K | B 32K), 2 barriers per 128-k chunk (half of R8's
// drain count). Epilogue: sC[128][68] roundtrip -> coalesced float4 stores.
// ---------------------------------------------------------------------------
__global__ __launch_bounds__(256, 2)
void mfma_adj(const float* __restrict__ adj,
              const unsigned short* __restrict__ BTa,
              const unsigned short* __restrict__ BTb,
              float* __restrict__ C, int ksplit, int zstride)
{
    __shared__ alignas(16) char smem[65536];   // A 32K | B 32K; sC overlays
    char* smA = smem;
    char* smB = smem + 32768;

    const int t    = threadIdx.x;
    const int l    = t & 63;
    const int w    = t >> 6;
    const int wr   = (w >> 1) * 64;
    const int wc   = (w & 1) * 64;
    const int lrow = l & 15;
    const int lhi  = l >> 4;
    const int i0   = blockIdx.x * 128;
    const int z    = blockIdx.z;
    const bool second = z >= 8;
    const unsigned short* BT = second ? BTb : BTa;
    const int kbase = (z & 7) * ksplit;
    C += (size_t)z * (size_t)zstride;

    const int srow = t >> 3;   // 0..31 (row-major staging)
    const int skg  = t & 7;    // 16B slot within 64-k half
    const int u    = t & 31;   // transposed staging: col group
    const int r8   = t >> 5;   // transposed staging: k-octet

    f32x4 acc[4][4];
    PRAGU
    for (int r = 0; r < 4; ++r)
        PRAGU
        for (int q = 0; q < 4; ++q)
            PRAGU
            for (int e = 0; e < 4; ++e) acc[r][q][e] = 0.0f;

    const int nt = ksplit >> 7;                // 8 chunks of 128 k
    for (int tc = 0; tc < nt; ++tc) {
        const int kk = kbase + tc * 128;

        PRAGU
        for (int h = 0; h < 2; ++h) {          // two 64-k halves per chunk
            const int kh = kk + h * 64;
            if (second) {
                // adj^T: thread owns adj rows [kh+r8*8,+8) x cols [i0+4u,+4).
                // 8 float4 loads (1KB/instr coalesced), register transpose.
                float4 rv[8];
                PRAGU
                for (int e = 0; e < 8; ++e)
                    rv[e] = ldg4(&adj[(size_t)(kh + r8 * 8 + e) * NN + i0 + u * 4]);
                PRAGU
                for (int j = 0; j < 4; ++j) {
                    const int c = u * 4 + j;
                    uint4 wv;
                    wv.x = f2bf2(FC(rv[0], j), FC(rv[1], j));
                    wv.y = f2bf2(FC(rv[2], j), FC(rv[3], j));
                    wv.z = f2bf2(FC(rv[4], j), FC(rv[5], j));
                    wv.w = f2bf2(FC(rv[6], j), FC(rv[7], j));
                    *reinterpret_cast<uint4*>(smA + c * 256 + lslot(c, h * 8 + r8)) = wv;
                }
            } else {
                PRAGU
                for (int it = 0; it < 4; ++it) {
                    const int row = it * 32 + srow;
                    const float* g = adj + (size_t)(i0 + row) * NN + kh + skg * 8;
                    float4 f0 = ldg4(g), f1 = ldg4(g + 4);
                    uint4 wv;
                    wv.x = f2bf2(f0.x, f0.y);
                    wv.y = f2bf2(f0.z, f0.w);
                    wv.z = f2bf2(f1.x, f1.y);
                    wv.w = f2bf2(f1.z, f1.w);
                    *reinterpret_cast<uint4*>(smA + row * 256 + lslot(row, h * 8 + skg)) = wv;
                }
            }
            // B: BT row-major [128][8192] bf16 (j0 = 0, N=128 is one tile)
            PRAGU
            for (int it = 0; it < 4; ++it) {
                const int n = it * 32 + srow;
                *reinterpret_cast<uint4*>(smB + n * 256 + lslot(n, h * 8 + skg)) =
                    *reinterpret_cast<const uint4*>(BT + (size_t)n * NN + kh + skg * 8);
            }
        }
        __syncthreads();

        PRAGU
        for (int s = 0; s < 4; ++s) {
            bf16x8 af[4], bq[4];
            PRAGU
            for (int r = 0; r < 4; ++r) {
                const int row = wr + r * 16 + lrow;
                af[r] = *reinterpret_cast<const bf16x8*>(smA + row * 256 + lslot(row, s * 4 + lhi));
            }
            PRAGU
            for (int q = 0; q < 4; ++q) {
                const int col = wc + q * 16 + lrow;
                bq[q] = *reinterpret_cast<const bf16x8*>(smB + col * 256 + lslot(col, s * 4 + lhi));
            }
            PRAGU
            for (int r = 0; r < 4; ++r)
                PRAGU
                for (int q = 0; q < 4; ++q)
                    acc[r][q] = __builtin_amdgcn_mfma_f32_16x16x32_bf16(af[r], bq[q], acc[r][q], 0, 0, 0);
        }
        __syncthreads();
    }

    // ---- epilogue: sC[128][68] roundtrip -> coalesced float4 stores ----
    float* sC = (float*)smem;
    PRAGU
    for (int h = 0; h < 2; ++h) {
        if ((w & 1) == h) {
            PRAGU
            for (int r = 0; r < 4; ++r)
                PRAGU
                for (int q = 0; q < 4; ++q)
                    PRAGU
                    for (int i = 0; i < 4; ++i)
                        sC[(wr + r * 16 + lhi * 4 + i) * 68 + q * 16 + lrow] = acc[r][q][i];
        }
        __syncthreads();
        PRAGU
        for (int it = 0; it < 8; ++it) {
            const int idx = it * 256 + t;
            const int row = idx >> 4;
            const int c4  = (idx & 15) << 2;
            f32x4 v = *reinterpret_cast<const f32x4*>(&sC[row * 68 + c4]);
            *reinterpret_cast<f32x4*>(&C[(size_t)(i0 + row) * DD + h * 64 + c4]) = v;
        }
        __syncthreads();
    }
}

// ---------------------------------------------------------------------------
// K8: adj2 tile = A[i-block] @ BT[j-block]^T.  A = p2n, BT = c2n, both
// [8192][128] bf16 row-major. K = 128 = ONE LDS stage, ONE barrier, 64 MFMAs,
// direct stores from acc (4-row x 64B segments — full HBM sectors).
// ---------------------------------------------------------------------------
__global__ __launch_bounds__(256, 2)
void mfma_out(const unsigned short* __restrict__ A,
              const unsigned short* __restrict__ BT,
              float* __restrict__ C)
{
    __shared__ alignas(16) char smem[65536];   // A 32K | B 32K
    char* smA = smem;
    char* smB = smem + 32768;

    const int t    = threadIdx.x;
    const int l    = t & 63;
    const int w    = t >> 6;
    const int wr   = (w >> 1) * 64;
    const int wc   = (w & 1) * 64;
    const int lrow = l & 15;
    const int lhi  = l >> 4;
    const int i0   = blockIdx.x * 128;
    const int j0   = blockIdx.y * 128;
    const int s16  = t >> 4;    // 0..15
    const int slot = t & 15;    // 0..15

    f32x4 acc[4][4];
    PRAGU
    for (int r = 0; r < 4; ++r)
        PRAGU
        for (int q = 0; q < 4; ++q)
            PRAGU
            for (int e = 0; e < 4; ++e) acc[r][q][e] = 0.0f;

    // single stage: 128 rows x 128 k bf16 each (1KB contiguous per instr)
    PRAGU
    for (int it = 0; it < 8; ++it) {
        const int row = it * 16 + s16;
        *reinterpret_cast<uint4*>(smA + row * 256 + lslot(row, slot)) =
            *reinterpret_cast<const uint4*>(A + (size_t)(i0 + row) * DD + slot * 8);
        *reinterpret_cast<uint4*>(smB + row * 256 + lslot(row, slot)) =
            *reinterpret_cast<const uint4*>(BT + (size_t)(j0 + row) * DD + slot * 8);
    }
    __syncthreads();

    PRAGU
    for (int s = 0; s < 4; ++s) {
        bf16x8 af[4], bq[4];
        PRAGU
        for (int r = 0; r < 4; ++r) {
            const int row = wr + r * 16 + lrow;
            af[r] = *reinterpret_cast<const bf16x8*>(smA + row * 256 + lslot(row, s * 4 + lhi));
        }
        PRAGU
        for (int q = 0; q < 4; ++q) {
            const int col = wc + q * 16 + lrow;
            bq[q] = *reinterpret_cast<const bf16x8*>(smB + col * 256 + lslot(col, s * 4 + lhi));
        }
        PRAGU
        for (int r = 0; r < 4; ++r)
            PRAGU
            for (int q = 0; q < 4; ++q)
                acc[r][q] = __builtin_amdgcn_mfma_f32_16x16x32_bf16(af[r], bq[q], acc[r][q], 0, 0, 0);
    }

    // direct stores: per instr 4 rows x 64B aligned segments
    PRAGU
    for (int r = 0; r < 4; ++r)
        PRAGU
        for (int i = 0; i < 4; ++i) {
            const int grow = i0 + wr + r * 16 + lhi * 4 + i;
            float* cp = C + (size_t)grow * NN + j0 + wc;
            PRAGU
            for (int q = 0; q < 4; ++q)
                cp[q * 16 + lrow] = acc[r][q][i];
        }
}

// ---------------------------------------------------------------------------
// K1: [pre|cur] @ W1 with fused transpose-bf16 epilogue.
// blockIdx.x < 256 -> pre rows -> pwT ; >= 256 -> cur rows -> cwT.
// ---------------------------------------------------------------------------
__global__ __launch_bounds__(256, 2)
void gemm_w1t(const float* __restrict__ pre, const float* __restrict__ cur,
              const float* __restrict__ W1,
              unsigned short* __restrict__ pwT, unsigned short* __restrict__ cwT)
{
    __shared__ float sA[32][68];
    __shared__ float sB[64][128];            // reused as sC[32][128]

    const int t  = threadIdx.x;
    const int ct = t & 31;
    const int rt = t >> 5;
    const int bx = blockIdx.x;
    const bool isCur = bx >= 256;
    const float* A = isCur ? cur : pre;
    unsigned short* XT = isCur ? cwT : pwT;
    const int i0 = (bx & 255) * 32;

    float4 acc[4];
    #pragma unroll
    for (int r = 0; r < 4; ++r) { acc[r].x = 0.f; acc[r].y = 0.f; acc[r].z = 0.f; acc[r].w = 0.f; }

    for (int k0 = 0; k0 < DD; k0 += 64) {
        #pragma unroll
        for (int f = 0; f < 2; ++f) {
            const int row = (t >> 4) + 16 * f;
            const int kk4 = (t & 15) << 2;
            *reinterpret_cast<float4*>(&sA[row][kk4]) =
                ldg4(&A[(size_t)(i0 + row) * DD + k0 + kk4]);
        }
        #pragma unroll
        for (int f = 0; f < 8; ++f) {
            const int idx = f * 256 + t;
            const int kk  = idx >> 5;
            const int c4  = (idx & 31) << 2;
            *reinterpret_cast<float4*>(&sB[kk][c4]) =
                ldg4(&W1[(size_t)(k0 + kk) * DD + c4]);
        }
        __syncthreads();
        #pragma unroll 4
        for (int kk = 0; kk < 64; kk += 4) {
            float4 a[4], b[4];
            #pragma unroll
            for (int r = 0; r < 4; ++r)
                a[r] = *reinterpret_cast<const float4*>(&sA[rt * 4 + r][kk]);
            #pragma unroll
            for (int q = 0; q < 4; ++q)
                b[q] = *reinterpret_cast<const float4*>(&sB[kk + q][ct * 4]);
            #pragma unroll
            for (int r = 0; r < 4; ++r) {
                acc[r].x += a[r].x * b[0].x; acc[r].y += a[r].x * b[0].y;
                acc[r].z += a[r].x * b[0].z; acc[r].w += a[r].x * b[0].w;
                acc[r].x += a[r].y * b[1].x; acc[r].y += a[r].y * b[1].y;
                acc[r].z += a[r].y * b[1].z; acc[r].w += a[r].y * b[1].w;
                acc[r].x += a[r].z * b[2].x; acc[r].y += a[r].z * b[2].y;
                acc[r].z += a[r].z * b[2].z; acc[r].w += a[r].z * b[2].w;
                acc[r].x += a[r].w * b[3].x; acc[r].y += a[r].w * b[3].y;
                acc[r].z += a[r].w * b[3].z; acc[r].w += a[r].w * b[3].w;
            }
        }
        __syncthreads();
    }

    // Transpose epilogue: acc -> sC[32][128] f32 -> bf16 XT[n][i0..i0+31]
    float* sC = &sB[0][0];
    #pragma unroll
    for (int r = 0; r < 4; ++r)
        *reinterpret_cast<float4*>(&sC[(rt * 4 + r) * 128 + ct * 4]) = acc[r];
    __syncthreads();

    const int n = t & 127;
    const int g = t >> 7;
    #pragma unroll
    for (int c = 0; c < 2; ++c) {
        const int ii = (2 * g + c) * 8;
        uint4 wv;
        wv.x = f2bf2(sC[(ii + 0) * 128 + n], sC[(ii + 1) * 128 + n]);
        wv.y = f2bf2(sC[(ii + 2) * 128 + n], sC[(ii + 3) * 128 + n]);
        wv.z = f2bf2(sC[(ii + 4) * 128 + n], sC[(ii + 5) * 128 + n]);
        wv.w = f2bf2(sC[(ii + 6) * 128 + n], sC[(ii + 7) * 128 + n]);
        *reinterpret_cast<uint4*>(&XT[(size_t)n * NN + i0 + ii]) = wv;
    }
}

// ---------------------------------------------------------------------------
// K3: stacked split-K reduce + leaky ReLU + inverse row norm.
// blockIdx.y = 0 -> c1 (kparts slots 8..15), 1 -> p1 (slots 0..7).
// ---------------------------------------------------------------------------
__global__ __launch_bounds__(128)
void rln(const float* __restrict__ kparts, float* __restrict__ Xbase,
         float* __restrict__ invbase)
{
    const int i = blockIdx.x;
    const int y = blockIdx.y;
    const int t = threadIdx.x;
    const float* part = kparts + (size_t)(1 - y) * 8 * (NN * DD);
    float* X = Xbase + (size_t)y * (NN * DD);
    float* inv_n = invbase + y * NN;

    float s = 0.f;
    #pragma unroll
    for (int z = 0; z < 8; ++z)
        s += part[(size_t)z * (NN * DD) + (size_t)i * DD + t];
    float y_ = (s >= 0.f) ? s : 0.01f * s;
    X[(size_t)i * DD + t] = y_;
    float n = y_ * y_;
    #pragma unroll
    for (int o = 32; o > 0; o >>= 1) n += __shfl_down(n, o);
    __shared__ float p[2];
    if ((t & 63) == 0) p[t >> 6] = n;
    __syncthreads();
    if (t == 0) inv_n[i] = 1.0f / sqrtf(p[0] + p[1]);
}

// ---------------------------------------------------------------------------
// fp32 tiled GEMM, N=128 fixed (j0=0); blockIdx.y = side with element strides
// ystA/ystB/ystC/ystS; blockIdx.z = split-K slice (C += z*zstride, EPI0).
//   EPI 0: raw fp32 store to C
//   EPI 3: y=leaky(acc*rscale[row]); row-norm via 32-lane shfl; bf16 to Cb.
//   SCALEK (with TRANSA): A *= kscale[k] during staging.
// ---------------------------------------------------------------------------
template<bool TRANSA, bool SCALEK, int EPI>
__global__ __launch_bounds__(256, 2)
void gemm32(const float* __restrict__ A, int lda,
            const float* __restrict__ B, int ldb,
            float* __restrict__ C, unsigned short* __restrict__ Cb,
            int ksplit_len, int zstride,
            const float* __restrict__ kscale,
            const float* __restrict__ rscale,
            int ystA, int ystB, int ystC, int ystS)
{
    __shared__ float sA[32][68];
    __shared__ float sB[64][128];

    const int t  = threadIdx.x;
    const int ct = t & 31;
    const int rt = t >> 5;
    const int i0 = blockIdx.x * 32;
    const int side = blockIdx.y;
    const int kgbase = blockIdx.z * ksplit_len;

    A += (ptrdiff_t)side * ystA;
    B += (ptrdiff_t)side * ystB;
    if constexpr (EPI == 0)
        C += (ptrdiff_t)side * ystC + (size_t)blockIdx.z * (size_t)zstride;
    if constexpr (EPI == 3)
        Cb += (ptrdiff_t)side * ystC;
    if constexpr (SCALEK) kscale += (ptrdiff_t)side * ystS;
    if constexpr (EPI == 3) rscale += (ptrdiff_t)side * ystS;

    float4 acc[4];
    #pragma unroll
    for (int r = 0; r < 4; ++r) { acc[r].x = 0.f; acc[r].y = 0.f; acc[r].z = 0.f; acc[r].w = 0.f; }

    for (int k0 = 0; k0 < ksplit_len; k0 += 64) {
        const int kg = kgbase + k0;
        if (!TRANSA) {
            #pragma unroll
            for (int f = 0; f < 2; ++f) {
                const int row = (t >> 4) + 16 * f;
                const int kk4 = (t & 15) << 2;
                *reinterpret_cast<float4*>(&sA[row][kk4]) =
                    ldg4(&A[(size_t)(i0 + row) * lda + kg + kk4]);
            }
        } else {
            #pragma unroll
            for (int f = 0; f < 2; ++f) {
                const int kk = (t >> 3) + 32 * f;
                const int r4 = (t & 7) << 2;
                float4 v = ldg4(&A[(size_t)(kg + kk) * lda + i0 + r4]);
                if (SCALEK) {
                    const float s = kscale[kg + kk];
                    v.x *= s; v.y *= s; v.z *= s; v.w *= s;
                }
                sA[r4 + 0][kk] = v.x; sA[r4 + 1][kk] = v.y;
                sA[r4 + 2][kk] = v.z; sA[r4 + 3][kk] = v.w;
            }
        }
        #pragma unroll
        for (int f = 0; f < 8; ++f) {
            const int idx = f * 256 + t;
            const int kk  = idx >> 5;
            const int c4  = (idx & 31) << 2;
            *reinterpret_cast<float4*>(&sB[kk][c4]) =
                ldg4(&B[(size_t)(kg + kk) * ldb + c4]);
        }
        __syncthreads();
        #pragma unroll 4
        for (int kk = 0; kk < 64; kk += 4) {
            float4 a[4], b[4];
            #pragma unroll
            for (int r = 0; r < 4; ++r)
                a[r] = *reinterpret_cast<const float4*>(&sA[rt * 4 + r][kk]);
            #pragma unroll
            for (int q = 0; q < 4; ++q)
                b[q] = *reinterpret_cast<const float4*>(&sB[kk + q][ct * 4]);
            #pragma unroll
            for (int r = 0; r < 4; ++r) {
                acc[r].x += a[r].x * b[0].x; acc[r].y += a[r].x * b[0].y;
                acc[r].z += a[r].x * b[0].z; acc[r].w += a[r].x * b[0].w;
                acc[r].x += a[r].y * b[1].x; acc[r].y += a[r].y * b[1].y;
                acc[r].z += a[r].y * b[1].z; acc[r].w += a[r].y * b[1].w;
                acc[r].x += a[r].z * b[2].x; acc[r].y += a[r].z * b[2].y;
                acc[r].z += a[r].z * b[2].z; acc[r].w += a[r].z * b[2].w;
                acc[r].x += a[r].w * b[3].x; acc[r].y += a[r].w * b[3].y;
                acc[r].z += a[r].w * b[3].z; acc[r].w += a[r].w * b[3].w;
            }
        }
        __syncthreads();
    }

    #pragma unroll
    for (int r = 0; r < 4; ++r) {
        const int rg = i0 + rt * 4 + r;
        if constexpr (EPI == 3) {
            const float s = rscale[rg];
            float y0 = acc[r].x * s, y1 = acc[r].y * s,
                  y2 = acc[r].z * s, y3 = acc[r].w * s;
            y0 = (y0 >= 0.f) ? y0 : 0.01f * y0;
            y1 = (y1 >= 0.f) ? y1 : 0.01f * y1;
            y2 = (y2 >= 0.f) ? y2 : 0.01f * y2;
            y3 = (y3 >= 0.f) ? y3 : 0.01f * y3;
            float ss = y0 * y0 + y1 * y1 + y2 * y2 + y3 * y3;
            #pragma unroll
            for (int m = 16; m > 0; m >>= 1) ss += __shfl_xor(ss, m);
            const float invn = rsqrtf(ss);
            uint2 wv;
            wv.x = f2bf2(y0 * invn, y1 * invn);
            wv.y = f2bf2(y2 * invn, y3 * invn);
            *reinterpret_cast<uint2*>(&Cb[(size_t)rg * DD + ct * 4]) = wv;
        } else {
            *reinterpret_cast<float4*>(&C[(size_t)rg * DD + ct * 4]) = acc[r];
        }
    }
}

// ---------------------------------------------------------------------------
// K6: stacked reduce for the brackets: out[y][i] = sum_z part[y][z][i].
// ---------------------------------------------------------------------------
__global__ __launch_bounds__(256)
void reduce_mcmp(const float* __restrict__ part, float* __restrict__ out)
{
    const int y = blockIdx.y;
    const int i = blockIdx.x * 256 + threadIdx.x;   // 0..16383
    part += (size_t)y * 32 * 16384;
    out  += (size_t)y * 16384;
    float a = 0.f;
    #pragma unroll
    for (int z = 0; z < 32; ++z) a += part[(size_t)z * 16384 + i];
    out[i] = a;
}

// ---------------------------------------------------------------------------
extern "C" void kernel_launch(void* const* d_in, const int* in_sizes, int n_in,
                              void* d_out, int out_size, void* d_ws, size_t ws_size,
                              hipStream_t stream)
{
    const float* pre = (const float*)d_in[0];
    const float* cur = (const float*)d_in[1];
    const float* adj = (const float*)d_in[2];
    const float* W1  = (const float*)d_in[3];
    const float* W2  = (const float*)d_in[4];
    float* out = (float*)d_out;
    float* ws  = (float*)d_ws;

    const size_t M1 = (size_t)NN * DD;   // 1,048,576

    // ws layout (~96 MB of 1 GiB); d_out untouched until K8.
    float* cwpw2 = ws + 0 * M1;                               // [cw2; pw2] 2*M1
    float* c1    = ws + 2 * M1;                               // c1 then p1 (contig)
    unsigned short* c2n_b = (unsigned short*)(ws + 4 * M1);   // c2n then p2n (bf16)
    unsigned short* p2n_b = c2n_b + M1;
    unsigned short* cwT_b = (unsigned short*)(ws + 5 * M1);   // [128][8192] bf16
    unsigned short* pwT_b = cwT_b + M1;
    float* bparts = ws + 6 * M1;                              // [2][32][16384]
    float* mcmp   = ws + 7 * M1;                              // [mc; mp] 32768
    float* inc1   = mcmp + 32768;                             // inc1 then inp1
    float* kparts = ws + 8 * M1;                              // [16][M1]

    // K1: [pre|cur]@W1 -> pwT_b / cwT_b (transposed bf16, no fp32 store)
    gemm_w1t<<<dim3(512,1,1),256,0,stream>>>(pre, cur, W1, pwT_b, cwT_b);

    // K2: combined adj pass, split-K 8 per side (1024 blocks).
    //     z<8: pre1 partials (adj@cwT) -> kparts[0..7];
    //     z>=8: cur1 partials (adjT@pwT) -> kparts[8..15].
    mfma_adj<<<dim3(64,1,16),256,0,stream>>>(adj, cwT_b, pwT_b,
                                             kparts, NN/8, (int)M1);

    // K3: stacked reduce+leaky+invnorm: y=0 -> c1/inc1, y=1 -> p1/inp1
    rln<<<dim3(NN,2,1),128,0,stream>>>(kparts, c1, inc1);

    // K4: [c1;p1]@W2 -> [cw2;pw2] (single M=16384 GEMM)
    gemm32<false,false,0><<<dim3(512,1,1),256,0,stream>>>(
        c1, DD, W2, DD, cwpw2, (unsigned short*)nullptr,
        DD, 0, nullptr, nullptr, 0,0,0,0);

    // K5: stacked brackets: side0 mc = (Dc^-1 c1)^T@cw2, side1 mp = (Dp^-1 p1)^T@pw2
    gemm32<true,true,0><<<dim3(4,2,32),256,0,stream>>>(
        c1, DD, cwpw2, DD, bparts, (unsigned short*)nullptr,
        256, 16384, inc1, nullptr,
        (int)M1, (int)M1, 32*16384, NN);

    // K6: stacked split-K reduce -> mcmp = [mc; mp]
    reduce_mcmp<<<dim3(64,2,1),256,0,stream>>>(bparts, mcmp);

    // K7: stacked fused tails (EPI3):
    //   side0: c2n = normrows(leaky(Dc^-1 c1 @ mp)) ; side1: p2n = ... (mc)
    gemm32<false,false,3><<<dim3(256,2,1),256,0,stream>>>(
        c1, DD, mcmp + 16384, DD, (float*)nullptr, c2n_b,
        DD, 0, nullptr, inc1,
        (int)M1, -16384, (int)M1, NN);

    // K8: adj2 = p2n @ c2n^T -> d_out (single-stage, one barrier)
    mfma_out<<<dim3(64,64,1),256,0,stream>>>(p2n_b, c2n_b, out);
}